// Round 29
// baseline (34.612 us; speedup 1.0000x reference)
//
#include <hip/hip_runtime.h>

// BertWordEmbedder: B=64, T=512, H=768, W=256, D=256
// R29 = R24 (confirmed best 34.4us x3) + T5 s_setprio(1) around the POOL
// waves' S2 body. S2 has genuine wave role-split (4 MFMA waves || 4 HBM-pool
// waves) and is pool-bound; prioritizing the latency-critical pool stream
// tests whether CU issue arbitration starves it behind MFMA bursts.
//   prep_wt2: proj_w -> wt2 TILED bf16 [ct=16][kc=96][16col][8k]
//   fused: S1 all-wave pool -> A0t; S2 waves 0-3 GEMM(A0t) || waves 4-7
//          pool A1t (setprio 1); S3 all-wave GEMM(A1t). Zero-barrier K-loops.
// Empty words: zero A row -> out = bias (matches reference).
// ws: [0) wt2 393216 B

#define NB 64
#define NT 512
#define NH 768
#define NW 256
#define ND 256
#define PAD 8
#define ROWE (NH + PAD)   // 776

typedef __attribute__((ext_vector_type(8))) short short8;
typedef __attribute__((ext_vector_type(4))) float f32x4;
typedef __attribute__((ext_vector_type(4))) float float4v;
typedef __attribute__((ext_vector_type(4))) unsigned short ushort4v;

__device__ __forceinline__ unsigned short f2bf(float f) {
    union { float f; unsigned u; } v; v.f = f;
    unsigned r = v.u + 0x7fffu + ((v.u >> 16) & 1u);  // RNE
    return (unsigned short)(r >> 16);
}

// proj_w -> tiled wt2: (k,col) at [((col>>4)*96 + (k>>3))*16 + (col&15)]*8 + (k&7)
__global__ void prep_wt2(const float* __restrict__ w, unsigned short* __restrict__ wt2) {
    __shared__ float tile[32][33];
    const int tid = threadIdx.x, n = blockIdx.x;
    const int tx = tid & 31, ty = tid >> 5;
    const int k0 = (n % 24) * 32, n0 = (n / 24) * 32;
    #pragma unroll
    for (int i = 0; i < 4; ++i)
        tile[ty + 8 * i][tx] = w[(size_t)(k0 + ty + 8 * i) * ND + n0 + tx];
    __syncthreads();
    if (tid < 128) {
        const int cc = tid & 31, q = tid >> 5;
        const int col = n0 + cc;
        ushort4v u0, u1;
        #pragma unroll
        for (int j = 0; j < 4; ++j) u0[j] = f2bf(tile[q * 8 + j][cc]);
        #pragma unroll
        for (int j = 0; j < 4; ++j) u1[j] = f2bf(tile[q * 8 + 4 + j][cc]);
        size_t off = (((size_t)(col >> 4) * 96 + (k0 >> 3) + q) * 16 + (col & 15)) * 8;
        *(ushort4v*)&wt2[off]     = u0;
        *(ushort4v*)&wt2[off + 4] = u1;
    }
}

// pool 4 words (sb[wi..wi+4]) as ONE contiguous token stream -> rows rr..rr+3
__device__ __forceinline__ void pool4(const int* __restrict__ sb, int wi,
                                      unsigned short (*__restrict__ At)[ROWE], int rr,
                                      const float* __restrict__ base, int lane) {
    const int s0 = sb[wi],     s1 = sb[wi + 1];
    const int s2 = sb[wi + 2], s3 = sb[wi + 3];
    const int s4 = sb[wi + 4];

    float4v acc[4][3];
    #pragma unroll
    for (int r = 0; r < 4; ++r)
        #pragma unroll
        for (int c = 0; c < 3; ++c)
            #pragma unroll
            for (int q = 0; q < 4; ++q) acc[r][c][q] = 0.f;

#define ADD3_(ar, vv) { _Pragma("unroll")                                     \
        for (int q = 0; q < 4; ++q) {                                         \
            ar[0][q] += (vv)[0][q]; ar[1][q] += (vv)[1][q]; ar[2][q] += (vv)[2][q]; } }
#define ROUTE4_(tt, vv) {                                                     \
        if ((tt) < s1)      { ADD3_(acc[0], vv); }                            \
        else if ((tt) < s2) { ADD3_(acc[1], vv); }                            \
        else if ((tt) < s3) { ADD3_(acc[2], vv); }                            \
        else                { ADD3_(acc[3], vv); } }

    int t = s0;
    for (; t + 4 <= s4; t += 4) {                    // 12 x 1KB loads in flight
        float4v v[4][3];
        #pragma unroll
        for (int u = 0; u < 4; ++u) {
            const float* p2 = base + (size_t)(t + u) * NH;
            v[u][0] = *(const float4v*)(p2);
            v[u][1] = *(const float4v*)(p2 + 256);
            v[u][2] = *(const float4v*)(p2 + 512);
        }
        #pragma unroll
        for (int u = 0; u < 4; ++u) ROUTE4_(t + u, v[u]);
    }
    for (; t < s4; ++t) {
        float4v v1[3];
        const float* p2 = base + (size_t)t * NH;
        v1[0] = *(const float4v*)(p2);
        v1[1] = *(const float4v*)(p2 + 256);
        v1[2] = *(const float4v*)(p2 + 512);
        ROUTE4_(t, v1);
    }
#undef ROUTE4_
#undef ADD3_

    #pragma unroll
    for (int r = 0; r < 4; ++r) {
        int cs = (r == 0) ? s0 : (r == 1) ? s1 : (r == 2) ? s2 : s3;
        int ce = (r == 0) ? s1 : (r == 1) ? s2 : (r == 2) ? s3 : s4;
        int cnt = ce - cs; if (cnt < 1) cnt = 1;
        const float sc = 1.0f / (float)cnt;
        #pragma unroll
        for (int c = 0; c < 3; ++c) {
            ushort4v u;
            #pragma unroll
            for (int q = 0; q < 4; ++q) u[q] = f2bf(acc[r][c][q] * sc);
            *(ushort4v*)&At[rr + r][c * 256 + lane * 4] = u;
        }
    }
}

// fused pipelined pool+GEMM. 256 blocks = (b, 64-word group), 512 thr.
__global__ __launch_bounds__(512, 2)
void fused(const float* __restrict__ hs, const int* __restrict__ wid,
           const unsigned short* __restrict__ wt2, const float* __restrict__ pb,
           float* __restrict__ out) {
    __shared__ unsigned short A0t[32][ROWE];   // 49664 B
    __shared__ unsigned short A1t[32][ROWE];   // 49664 B
    __shared__ int swid[NT];
    __shared__ int sb[65];

    const int tid = threadIdx.x, bid = blockIdx.x;
    const int wave = tid >> 6, lane = tid & 63;
    const int b = bid >> 2, W0 = (bid & 3) * 64;

    swid[tid] = wid[b * NT + tid];
    __syncthreads();
    if (tid <= 64) {
        int v = W0 + tid, lo = 0, hi = NT;
        while (lo < hi) { int mid = (lo + hi) >> 1; if (swid[mid] < v) lo = mid + 1; else hi = mid; }
        sb[tid] = lo;
    }
    __syncthreads();

    const float* base = hs + (size_t)b * NT * NH + lane * 4;
    const int cl = lane & 15, kg = lane >> 4;

    // ---- Stage 1: A0 (all 8 waves, 4 words each; lockstep -> no setprio) ----
    pool4(sb, wave * 4, A0t, wave * 4, base, lane);
    __syncthreads();

    // ---- Stage 2: waves 0-3 GEMM(A0t) 32x256  ||  waves 4-7 pool A1 ----
    if (wave < 4) {
        const int c0w = wave * 64;
        const unsigned short* bgp = wt2 + (size_t)(wave * 4) * 12288 + kg * 128 + cl * 8;
        short8 a0[2], a1[2], b0[4], b1[4];
        f32x4 acc[2][4];
        #pragma unroll
        for (int mt = 0; mt < 2; ++mt)
            #pragma unroll
            for (int nt = 0; nt < 4; ++nt)
                #pragma unroll
                for (int r = 0; r < 4; ++r) acc[mt][nt][r] = 0.f;

#define LDA0(d, ks) { d[0] = *(const short8*)&A0t[cl][(ks) * 32 + kg * 8];    \
                      d[1] = *(const short8*)&A0t[16 + cl][(ks) * 32 + kg * 8]; }
#define LDB0(d, ks) { _Pragma("unroll")                                       \
                      for (int nt = 0; nt < 4; ++nt)                          \
                          d[nt] = *(const short8*)(bgp + nt * 12288 + (ks) * 512); }
#define MM0(a, bb) { _Pragma("unroll")                                        \
                     for (int mt = 0; mt < 2; ++mt)                           \
                         _Pragma("unroll")                                    \
                         for (int nt = 0; nt < 4; ++nt)                       \
                             acc[mt][nt] = __builtin_amdgcn_mfma_f32_16x16x32_bf16(a[mt], bb[nt], acc[mt][nt], 0, 0, 0); }

        LDA0(a0, 0); LDB0(b0, 0);
        #pragma unroll 1
        for (int i = 0; i < 12; ++i) {
            const int ks = 2 * i;
            LDA0(a1, ks + 1); LDB0(b1, ks + 1);
            MM0(a0, b0);
            if (i < 11) { LDA0(a0, ks + 2); LDB0(b0, ks + 2); }
            MM0(a1, b1);
        }
#undef LDA0
#undef LDB0
#undef MM0

        float bv[4];
        #pragma unroll
        for (int nt = 0; nt < 4; ++nt) bv[nt] = pb[c0w + nt * 16 + cl];

        #pragma unroll
        for (int mt = 0; mt < 2; ++mt)
            #pragma unroll
            for (int nt = 0; nt < 4; ++nt)
                #pragma unroll
                for (int r = 0; r < 4; ++r)
                    out[((size_t)b * NW + W0 + mt * 16 + kg * 4 + r) * ND + c0w + nt * 16 + cl]
                        = acc[mt][nt][r] + bv[nt];
    } else {
        // T5 (inverted): pool waves are S2's critical path -> prioritize them
        __builtin_amdgcn_s_setprio(1);
        const int wv = wave - 4;
        pool4(sb, 32 + wv * 8,     A1t, wv * 8,     base, lane);
        pool4(sb, 32 + wv * 8 + 4, A1t, wv * 8 + 4, base, lane);
        __builtin_amdgcn_s_setprio(0);
    }
    __syncthreads();

    // ---- Stage 3: all 8 waves GEMM(A1t) 32x256; wave = 32x32 (2Mx2N) ----
    {
        const int c0w = wave * 32;
        const unsigned short* bgp = wt2 + (size_t)(wave * 2) * 12288 + kg * 128 + cl * 8;
        short8 a0f[2], a1f[2], b0f[2], b1f[2];
        f32x4 acc[2][2];
        #pragma unroll
        for (int mt = 0; mt < 2; ++mt)
            #pragma unroll
            for (int nt = 0; nt < 2; ++nt)
                #pragma unroll
                for (int r = 0; r < 4; ++r) acc[mt][nt][r] = 0.f;

#define LDA1(d, ks) { d[0] = *(const short8*)&A1t[cl][(ks) * 32 + kg * 8];    \
                      d[1] = *(const short8*)&A1t[16 + cl][(ks) * 32 + kg * 8]; }
#define LDB1(d, ks) { _Pragma("unroll")                                       \
                      for (int nt = 0; nt < 2; ++nt)                          \
                          d[nt] = *(const short8*)(bgp + nt * 12288 + (ks) * 512); }
#define MM1(a, bb) { _Pragma("unroll")                                        \
                     for (int mt = 0; mt < 2; ++mt)                           \
                         _Pragma("unroll")                                    \
                         for (int nt = 0; nt < 2; ++nt)                       \
                             acc[mt][nt] = __builtin_amdgcn_mfma_f32_16x16x32_bf16(a[mt], bb[nt], acc[mt][nt], 0, 0, 0); }

        LDA1(a0f, 0); LDB1(b0f, 0);
        #pragma unroll 1
        for (int i = 0; i < 12; ++i) {
            const int ks = 2 * i;
            LDA1(a1f, ks + 1); LDB1(b1f, ks + 1);
            MM1(a0f, b0f);
            if (i < 11) { LDA1(a0f, ks + 2); LDB1(b0f, ks + 2); }
            MM1(a1f, b1f);
        }
#undef LDA1
#undef LDB1
#undef MM1

        float bv[2];
        bv[0] = pb[c0w + cl];
        bv[1] = pb[c0w + 16 + cl];

        // C/D layout: col=lane&15, row=(lane>>4)*4+r  [proven R1-R28]
        #pragma unroll
        for (int mt = 0; mt < 2; ++mt)
            #pragma unroll
            for (int nt = 0; nt < 2; ++nt)
                #pragma unroll
                for (int r = 0; r < 4; ++r)
                    out[((size_t)b * NW + W0 + 32 + mt * 16 + kg * 4 + r) * ND + c0w + nt * 16 + cl]
                        = acc[mt][nt][r] + bv[nt];
    }
}

extern "C" void kernel_launch(void* const* d_in, const int* in_sizes, int n_in,
                              void* d_out, int out_size, void* d_ws, size_t ws_size,
                              hipStream_t stream) {
    const float* hs  = (const float*)d_in[0];
    const int*   wid = (const int*)d_in[1];
    const float* pw  = (const float*)d_in[2];
    const float* pb  = (const float*)d_in[3];
    float* out = (float*)d_out;

    unsigned short* wt2 = (unsigned short*)d_ws;     // 393216 B

    prep_wt2<<<192, 256, 0, stream>>>(pw, wt2);
    fused<<<NB * 4, 512, 0, stream>>>(hs, wid, wt2, pb, out);
}

// Round 30
// 34.359 us; speedup vs baseline: 1.0074x; 1.0074x over previous
//
#include <hip/hip_runtime.h>

// BertWordEmbedder: B=64, T=512, H=768, W=256, D=256
// TERMINAL KERNEL (= R24, reproducible best 34.39/34.44/34.47us).
//   prep_wt2: proj_w -> wt2 TILED bf16 [ct=16][kc=96][16col][8k]
//   fused:    256 blocks = (b, 64-word group), 512 thr / 8 waves, 1 block/CU.
//     S1: all 8 waves pool words [W0,W0+32) -> A0t (4 words/wave, contiguous
//         token stream, 4-token unroll = 12 loads in flight, 4-way routing).
//     S2: waves 0-3 GEMM(A0t) 32x256 (wave=32x64)  ||  waves 4-7 pool
//         [W0+32,W0+64) -> A1t (2x pool4 each).
//     S3: all 8 waves GEMM(A1t) (wave=32x32). Zero-barrier K-loops, B direct
//         from L2-resident tiled wt2, ping-pong register prefetch.
// Empty words: zero A row -> out = bias (matches reference).
// Session ledger (50.7 -> 34.4, 2.1x): wins = LDS-staged GEMM (R6), zero-we
// fusion + tiled-B direct-from-L2 (R15, -7us), 8-wave phase A (R18/19),
// intra-block 2-tile pipeline (R24, -0.6). Refuted (15 hypotheses): ILP
// depth 2/4/8-token, forced occupancy, task granularity, col-interleave,
// load balance, coop-launch, in-loop pool fusion, single-kernel flag fusion
// (R22: VGPR 128->60 codegen collapse), S2 rebalance (R25), setprio on pool
// waves (R29: null). Plateau: hs stream at ~52% of per-CU HBM share with
// ample outstanding bytes -> limiter is sub-source (memory-system), and
// codegen-sensitive restructuring regresses. Counters: 10% HBM / 12% VALU /
// 4% MFMA — latency plateau, not a BW or compute wall.
// ws: [0) wt2 393216 B

#define NB 64
#define NT 512
#define NH 768
#define NW 256
#define ND 256
#define PAD 8
#define ROWE (NH + PAD)   // 776

typedef __attribute__((ext_vector_type(8))) short short8;
typedef __attribute__((ext_vector_type(4))) float f32x4;
typedef __attribute__((ext_vector_type(4))) float float4v;
typedef __attribute__((ext_vector_type(4))) unsigned short ushort4v;

__device__ __forceinline__ unsigned short f2bf(float f) {
    union { float f; unsigned u; } v; v.f = f;
    unsigned r = v.u + 0x7fffu + ((v.u >> 16) & 1u);  // RNE
    return (unsigned short)(r >> 16);
}

// proj_w -> tiled wt2: (k,col) at [((col>>4)*96 + (k>>3))*16 + (col&15)]*8 + (k&7)
__global__ void prep_wt2(const float* __restrict__ w, unsigned short* __restrict__ wt2) {
    __shared__ float tile[32][33];
    const int tid = threadIdx.x, n = blockIdx.x;
    const int tx = tid & 31, ty = tid >> 5;
    const int k0 = (n % 24) * 32, n0 = (n / 24) * 32;
    #pragma unroll
    for (int i = 0; i < 4; ++i)
        tile[ty + 8 * i][tx] = w[(size_t)(k0 + ty + 8 * i) * ND + n0 + tx];
    __syncthreads();
    if (tid < 128) {
        const int cc = tid & 31, q = tid >> 5;
        const int col = n0 + cc;
        ushort4v u0, u1;
        #pragma unroll
        for (int j = 0; j < 4; ++j) u0[j] = f2bf(tile[q * 8 + j][cc]);
        #pragma unroll
        for (int j = 0; j < 4; ++j) u1[j] = f2bf(tile[q * 8 + 4 + j][cc]);
        size_t off = (((size_t)(col >> 4) * 96 + (k0 >> 3) + q) * 16 + (col & 15)) * 8;
        *(ushort4v*)&wt2[off]     = u0;
        *(ushort4v*)&wt2[off + 4] = u1;
    }
}

// pool 4 words (sb[wi..wi+4]) as ONE contiguous token stream -> rows rr..rr+3
__device__ __forceinline__ void pool4(const int* __restrict__ sb, int wi,
                                      unsigned short (*__restrict__ At)[ROWE], int rr,
                                      const float* __restrict__ base, int lane) {
    const int s0 = sb[wi],     s1 = sb[wi + 1];
    const int s2 = sb[wi + 2], s3 = sb[wi + 3];
    const int s4 = sb[wi + 4];

    float4v acc[4][3];
    #pragma unroll
    for (int r = 0; r < 4; ++r)
        #pragma unroll
        for (int c = 0; c < 3; ++c)
            #pragma unroll
            for (int q = 0; q < 4; ++q) acc[r][c][q] = 0.f;

#define ADD3_(ar, vv) { _Pragma("unroll")                                     \
        for (int q = 0; q < 4; ++q) {                                         \
            ar[0][q] += (vv)[0][q]; ar[1][q] += (vv)[1][q]; ar[2][q] += (vv)[2][q]; } }
#define ROUTE4_(tt, vv) {                                                     \
        if ((tt) < s1)      { ADD3_(acc[0], vv); }                            \
        else if ((tt) < s2) { ADD3_(acc[1], vv); }                            \
        else if ((tt) < s3) { ADD3_(acc[2], vv); }                            \
        else                { ADD3_(acc[3], vv); } }

    int t = s0;
    for (; t + 4 <= s4; t += 4) {                    // 12 x 1KB loads in flight
        float4v v[4][3];
        #pragma unroll
        for (int u = 0; u < 4; ++u) {
            const float* p2 = base + (size_t)(t + u) * NH;
            v[u][0] = *(const float4v*)(p2);
            v[u][1] = *(const float4v*)(p2 + 256);
            v[u][2] = *(const float4v*)(p2 + 512);
        }
        #pragma unroll
        for (int u = 0; u < 4; ++u) ROUTE4_(t + u, v[u]);
    }
    for (; t < s4; ++t) {
        float4v v1[3];
        const float* p2 = base + (size_t)t * NH;
        v1[0] = *(const float4v*)(p2);
        v1[1] = *(const float4v*)(p2 + 256);
        v1[2] = *(const float4v*)(p2 + 512);
        ROUTE4_(t, v1);
    }
#undef ROUTE4_
#undef ADD3_

    #pragma unroll
    for (int r = 0; r < 4; ++r) {
        int cs = (r == 0) ? s0 : (r == 1) ? s1 : (r == 2) ? s2 : s3;
        int ce = (r == 0) ? s1 : (r == 1) ? s2 : (r == 2) ? s3 : s4;
        int cnt = ce - cs; if (cnt < 1) cnt = 1;
        const float sc = 1.0f / (float)cnt;
        #pragma unroll
        for (int c = 0; c < 3; ++c) {
            ushort4v u;
            #pragma unroll
            for (int q = 0; q < 4; ++q) u[q] = f2bf(acc[r][c][q] * sc);
            *(ushort4v*)&At[rr + r][c * 256 + lane * 4] = u;
        }
    }
}

// fused pipelined pool+GEMM. 256 blocks = (b, 64-word group), 512 thr.
__global__ __launch_bounds__(512, 2)
void fused(const float* __restrict__ hs, const int* __restrict__ wid,
           const unsigned short* __restrict__ wt2, const float* __restrict__ pb,
           float* __restrict__ out) {
    __shared__ unsigned short A0t[32][ROWE];   // 49664 B
    __shared__ unsigned short A1t[32][ROWE];   // 49664 B
    __shared__ int swid[NT];
    __shared__ int sb[65];

    const int tid = threadIdx.x, bid = blockIdx.x;
    const int wave = tid >> 6, lane = tid & 63;
    const int b = bid >> 2, W0 = (bid & 3) * 64;

    swid[tid] = wid[b * NT + tid];
    __syncthreads();
    if (tid <= 64) {
        int v = W0 + tid, lo = 0, hi = NT;
        while (lo < hi) { int mid = (lo + hi) >> 1; if (swid[mid] < v) lo = mid + 1; else hi = mid; }
        sb[tid] = lo;
    }
    __syncthreads();

    const float* base = hs + (size_t)b * NT * NH + lane * 4;
    const int cl = lane & 15, kg = lane >> 4;

    // ---- Stage 1: A0 (all 8 waves, 4 words each) ----
    pool4(sb, wave * 4, A0t, wave * 4, base, lane);
    __syncthreads();

    // ---- Stage 2: waves 0-3 GEMM(A0t) 32x256  ||  waves 4-7 pool A1 ----
    if (wave < 4) {
        const int c0w = wave * 64;
        const unsigned short* bgp = wt2 + (size_t)(wave * 4) * 12288 + kg * 128 + cl * 8;
        short8 a0[2], a1[2], b0[4], b1[4];
        f32x4 acc[2][4];
        #pragma unroll
        for (int mt = 0; mt < 2; ++mt)
            #pragma unroll
            for (int nt = 0; nt < 4; ++nt)
                #pragma unroll
                for (int r = 0; r < 4; ++r) acc[mt][nt][r] = 0.f;

#define LDA0(d, ks) { d[0] = *(const short8*)&A0t[cl][(ks) * 32 + kg * 8];    \
                      d[1] = *(const short8*)&A0t[16 + cl][(ks) * 32 + kg * 8]; }
#define LDB0(d, ks) { _Pragma("unroll")                                       \
                      for (int nt = 0; nt < 4; ++nt)                          \
                          d[nt] = *(const short8*)(bgp + nt * 12288 + (ks) * 512); }
#define MM0(a, bb) { _Pragma("unroll")                                        \
                     for (int mt = 0; mt < 2; ++mt)                           \
                         _Pragma("unroll")                                    \
                         for (int nt = 0; nt < 4; ++nt)                       \
                             acc[mt][nt] = __builtin_amdgcn_mfma_f32_16x16x32_bf16(a[mt], bb[nt], acc[mt][nt], 0, 0, 0); }

        LDA0(a0, 0); LDB0(b0, 0);
        #pragma unroll 1
        for (int i = 0; i < 12; ++i) {
            const int ks = 2 * i;
            LDA0(a1, ks + 1); LDB0(b1, ks + 1);
            MM0(a0, b0);
            if (i < 11) { LDA0(a0, ks + 2); LDB0(b0, ks + 2); }
            MM0(a1, b1);
        }
#undef LDA0
#undef LDB0
#undef MM0

        float bv[4];
        #pragma unroll
        for (int nt = 0; nt < 4; ++nt) bv[nt] = pb[c0w + nt * 16 + cl];

        #pragma unroll
        for (int mt = 0; mt < 2; ++mt)
            #pragma unroll
            for (int nt = 0; nt < 4; ++nt)
                #pragma unroll
                for (int r = 0; r < 4; ++r)
                    out[((size_t)b * NW + W0 + mt * 16 + kg * 4 + r) * ND + c0w + nt * 16 + cl]
                        = acc[mt][nt][r] + bv[nt];
    } else {
        const int wv = wave - 4;
        pool4(sb, 32 + wv * 8,     A1t, wv * 8,     base, lane);
        pool4(sb, 32 + wv * 8 + 4, A1t, wv * 8 + 4, base, lane);
    }
    __syncthreads();

    // ---- Stage 3: all 8 waves GEMM(A1t) 32x256; wave = 32x32 (2Mx2N) ----
    {
        const int c0w = wave * 32;
        const unsigned short* bgp = wt2 + (size_t)(wave * 2) * 12288 + kg * 128 + cl * 8;
        short8 a0f[2], a1f[2], b0f[2], b1f[2];
        f32x4 acc[2][2];
        #pragma unroll
        for (int mt = 0; mt < 2; ++mt)
            #pragma unroll
            for (int nt = 0; nt < 2; ++nt)
                #pragma unroll
                for (int r = 0; r < 4; ++r) acc[mt][nt][r] = 0.f;

#define LDA1(d, ks) { d[0] = *(const short8*)&A1t[cl][(ks) * 32 + kg * 8];    \
                      d[1] = *(const short8*)&A1t[16 + cl][(ks) * 32 + kg * 8]; }
#define LDB1(d, ks) { _Pragma("unroll")                                       \
                      for (int nt = 0; nt < 2; ++nt)                          \
                          d[nt] = *(const short8*)(bgp + nt * 12288 + (ks) * 512); }
#define MM1(a, bb) { _Pragma("unroll")                                        \
                     for (int mt = 0; mt < 2; ++mt)                           \
                         _Pragma("unroll")                                    \
                         for (int nt = 0; nt < 2; ++nt)                       \
                             acc[mt][nt] = __builtin_amdgcn_mfma_f32_16x16x32_bf16(a[mt], bb[nt], acc[mt][nt], 0, 0, 0); }

        LDA1(a0f, 0); LDB1(b0f, 0);
        #pragma unroll 1
        for (int i = 0; i < 12; ++i) {
            const int ks = 2 * i;
            LDA1(a1f, ks + 1); LDB1(b1f, ks + 1);
            MM1(a0f, b0f);
            if (i < 11) { LDA1(a0f, ks + 2); LDB1(b0f, ks + 2); }
            MM1(a1f, b1f);
        }
#undef LDA1
#undef LDB1
#undef MM1

        float bv[2];
        bv[0] = pb[c0w + cl];
        bv[1] = pb[c0w + 16 + cl];

        // C/D layout: col=lane&15, row=(lane>>4)*4+r  [proven R1-R29]
        #pragma unroll
        for (int mt = 0; mt < 2; ++mt)
            #pragma unroll
            for (int nt = 0; nt < 2; ++nt)
                #pragma unroll
                for (int r = 0; r < 4; ++r)
                    out[((size_t)b * NW + W0 + 32 + mt * 16 + kg * 4 + r) * ND + c0w + nt * 16 + cl]
                        = acc[mt][nt][r] + bv[nt];
    }
}

extern "C" void kernel_launch(void* const* d_in, const int* in_sizes, int n_in,
                              void* d_out, int out_size, void* d_ws, size_t ws_size,
                              hipStream_t stream) {
    const float* hs  = (const float*)d_in[0];
    const int*   wid = (const int*)d_in[1];
    const float* pw  = (const float*)d_in[2];
    const float* pb  = (const float*)d_in[3];
    float* out = (float*)d_out;

    unsigned short* wt2 = (unsigned short*)d_ws;     // 393216 B

    prep_wt2<<<192, 256, 0, stream>>>(pw, wt2);
    fused<<<NB * 4, 512, 0, stream>>>(hs, wid, wt2, pb, out);
}

// Round 31
// 34.173 us; speedup vs baseline: 1.0128x; 1.0054x over previous
//
#include <hip/hip_runtime.h>

// BertWordEmbedder: B=64, T=512, H=768, W=256, D=256
// R31 = R24 (best 34.4us x5) with BRANCHLESS pool routing: ROUTE4's
// s_cmp/s_cbranch chains gate load issue (compiler can't hoist next batch's
// loads across branchy accumulates -> pipeline drains every 4 tokens, which
// also explains R27's deep-unroll null). Replace with 4 uniform 0/1 masks +
// v_fmac into all 4 accumulator sets: straight-line body, scheduler free to
// software-pipeline loads. VALU cost ~4x but VALU is 12% busy (headroom).
//   prep_wt2: proj_w -> wt2 TILED bf16 [ct=16][kc=96][16col][8k]
//   fused: S1 all-wave pool -> A0t; S2 waves 0-3 GEMM(A0t) || waves 4-7
//          pool A1t; S3 all-wave GEMM(A1t). Zero-barrier K-loops.
// Empty words: zero A row -> out = bias (matches reference).
// ws: [0) wt2 393216 B

#define NB 64
#define NT 512
#define NH 768
#define NW 256
#define ND 256
#define PAD 8
#define ROWE (NH + PAD)   // 776

typedef __attribute__((ext_vector_type(8))) short short8;
typedef __attribute__((ext_vector_type(4))) float f32x4;
typedef __attribute__((ext_vector_type(4))) float float4v;
typedef __attribute__((ext_vector_type(4))) unsigned short ushort4v;

__device__ __forceinline__ unsigned short f2bf(float f) {
    union { float f; unsigned u; } v; v.f = f;
    unsigned r = v.u + 0x7fffu + ((v.u >> 16) & 1u);  // RNE
    return (unsigned short)(r >> 16);
}

// proj_w -> tiled wt2: (k,col) at [((col>>4)*96 + (k>>3))*16 + (col&15)]*8 + (k&7)
__global__ void prep_wt2(const float* __restrict__ w, unsigned short* __restrict__ wt2) {
    __shared__ float tile[32][33];
    const int tid = threadIdx.x, n = blockIdx.x;
    const int tx = tid & 31, ty = tid >> 5;
    const int k0 = (n % 24) * 32, n0 = (n / 24) * 32;
    #pragma unroll
    for (int i = 0; i < 4; ++i)
        tile[ty + 8 * i][tx] = w[(size_t)(k0 + ty + 8 * i) * ND + n0 + tx];
    __syncthreads();
    if (tid < 128) {
        const int cc = tid & 31, q = tid >> 5;
        const int col = n0 + cc;
        ushort4v u0, u1;
        #pragma unroll
        for (int j = 0; j < 4; ++j) u0[j] = f2bf(tile[q * 8 + j][cc]);
        #pragma unroll
        for (int j = 0; j < 4; ++j) u1[j] = f2bf(tile[q * 8 + 4 + j][cc]);
        size_t off = (((size_t)(col >> 4) * 96 + (k0 >> 3) + q) * 16 + (col & 15)) * 8;
        *(ushort4v*)&wt2[off]     = u0;
        *(ushort4v*)&wt2[off + 4] = u1;
    }
}

// pool 4 words (sb[wi..wi+4]) as ONE contiguous token stream -> rows rr..rr+3
// R31: branchless mask-FMA routing (uniform 0/1 masks; straight-line body).
__device__ __forceinline__ void pool4(const int* __restrict__ sb, int wi,
                                      unsigned short (*__restrict__ At)[ROWE], int rr,
                                      const float* __restrict__ base, int lane) {
    const int s0 = sb[wi],     s1 = sb[wi + 1];
    const int s2 = sb[wi + 2], s3 = sb[wi + 3];
    const int s4 = sb[wi + 4];

    float4v acc[4][3];
    #pragma unroll
    for (int r = 0; r < 4; ++r)
        #pragma unroll
        for (int c = 0; c < 3; ++c)
            #pragma unroll
            for (int q = 0; q < 4; ++q) acc[r][c][q] = 0.f;

    // branchless accumulate of one token's 3 chunks into the 4 acc sets
#define ROUTEM_(tt, vv) {                                                     \
        const float m1_ = ((tt) < s1) ? 1.f : 0.f;                            \
        const float m2_ = ((tt) >= s1 && (tt) < s2) ? 1.f : 0.f;              \
        const float m3_ = ((tt) >= s2 && (tt) < s3) ? 1.f : 0.f;              \
        const float m4_ = ((tt) >= s3) ? 1.f : 0.f;                           \
        _Pragma("unroll")                                                     \
        for (int c_ = 0; c_ < 3; ++c_)                                        \
            _Pragma("unroll")                                                 \
            for (int q_ = 0; q_ < 4; ++q_) {                                  \
                acc[0][c_][q_] += (vv)[c_][q_] * m1_;                         \
                acc[1][c_][q_] += (vv)[c_][q_] * m2_;                         \
                acc[2][c_][q_] += (vv)[c_][q_] * m3_;                         \
                acc[3][c_][q_] += (vv)[c_][q_] * m4_;                         \
            }                                                                 \
    }

    int t = s0;
    for (; t + 4 <= s4; t += 4) {                    // 12 x 1KB loads in flight
        float4v v[4][3];
        #pragma unroll
        for (int u = 0; u < 4; ++u) {
            const float* p2 = base + (size_t)(t + u) * NH;
            v[u][0] = *(const float4v*)(p2);
            v[u][1] = *(const float4v*)(p2 + 256);
            v[u][2] = *(const float4v*)(p2 + 512);
        }
        #pragma unroll
        for (int u = 0; u < 4; ++u) ROUTEM_(t + u, v[u]);
    }
    for (; t < s4; ++t) {
        float4v v1[3];
        const float* p2 = base + (size_t)t * NH;
        v1[0] = *(const float4v*)(p2);
        v1[1] = *(const float4v*)(p2 + 256);
        v1[2] = *(const float4v*)(p2 + 512);
        ROUTEM_(t, v1);
    }
#undef ROUTEM_

    #pragma unroll
    for (int r = 0; r < 4; ++r) {
        int cs = (r == 0) ? s0 : (r == 1) ? s1 : (r == 2) ? s2 : s3;
        int ce = (r == 0) ? s1 : (r == 1) ? s2 : (r == 2) ? s3 : s4;
        int cnt = ce - cs; if (cnt < 1) cnt = 1;
        const float sc = 1.0f / (float)cnt;
        #pragma unroll
        for (int c = 0; c < 3; ++c) {
            ushort4v u;
            #pragma unroll
            for (int q = 0; q < 4; ++q) u[q] = f2bf(acc[r][c][q] * sc);
            *(ushort4v*)&At[rr + r][c * 256 + lane * 4] = u;
        }
    }
}

// fused pipelined pool+GEMM. 256 blocks = (b, 64-word group), 512 thr.
__global__ __launch_bounds__(512, 2)
void fused(const float* __restrict__ hs, const int* __restrict__ wid,
           const unsigned short* __restrict__ wt2, const float* __restrict__ pb,
           float* __restrict__ out) {
    __shared__ unsigned short A0t[32][ROWE];   // 49664 B
    __shared__ unsigned short A1t[32][ROWE];   // 49664 B
    __shared__ int swid[NT];
    __shared__ int sb[65];

    const int tid = threadIdx.x, bid = blockIdx.x;
    const int wave = tid >> 6, lane = tid & 63;
    const int b = bid >> 2, W0 = (bid & 3) * 64;

    swid[tid] = wid[b * NT + tid];
    __syncthreads();
    if (tid <= 64) {
        int v = W0 + tid, lo = 0, hi = NT;
        while (lo < hi) { int mid = (lo + hi) >> 1; if (swid[mid] < v) lo = mid + 1; else hi = mid; }
        sb[tid] = lo;
    }
    __syncthreads();

    const float* base = hs + (size_t)b * NT * NH + lane * 4;
    const int cl = lane & 15, kg = lane >> 4;

    // ---- Stage 1: A0 (all 8 waves, 4 words each) ----
    pool4(sb, wave * 4, A0t, wave * 4, base, lane);
    __syncthreads();

    // ---- Stage 2: waves 0-3 GEMM(A0t) 32x256  ||  waves 4-7 pool A1 ----
    if (wave < 4) {
        const int c0w = wave * 64;
        const unsigned short* bgp = wt2 + (size_t)(wave * 4) * 12288 + kg * 128 + cl * 8;
        short8 a0[2], a1[2], b0[4], b1[4];
        f32x4 acc[2][4];
        #pragma unroll
        for (int mt = 0; mt < 2; ++mt)
            #pragma unroll
            for (int nt = 0; nt < 4; ++nt)
                #pragma unroll
                for (int r = 0; r < 4; ++r) acc[mt][nt][r] = 0.f;

#define LDA0(d, ks) { d[0] = *(const short8*)&A0t[cl][(ks) * 32 + kg * 8];    \
                      d[1] = *(const short8*)&A0t[16 + cl][(ks) * 32 + kg * 8]; }
#define LDB0(d, ks) { _Pragma("unroll")                                       \
                      for (int nt = 0; nt < 4; ++nt)                          \
                          d[nt] = *(const short8*)(bgp + nt * 12288 + (ks) * 512); }
#define MM0(a, bb) { _Pragma("unroll")                                        \
                     for (int mt = 0; mt < 2; ++mt)                           \
                         _Pragma("unroll")                                    \
                         for (int nt = 0; nt < 4; ++nt)                       \
                             acc[mt][nt] = __builtin_amdgcn_mfma_f32_16x16x32_bf16(a[mt], bb[nt], acc[mt][nt], 0, 0, 0); }

        LDA0(a0, 0); LDB0(b0, 0);
        #pragma unroll 1
        for (int i = 0; i < 12; ++i) {
            const int ks = 2 * i;
            LDA0(a1, ks + 1); LDB0(b1, ks + 1);
            MM0(a0, b0);
            if (i < 11) { LDA0(a0, ks + 2); LDB0(b0, ks + 2); }
            MM0(a1, b1);
        }
#undef LDA0
#undef LDB0
#undef MM0

        float bv[4];
        #pragma unroll
        for (int nt = 0; nt < 4; ++nt) bv[nt] = pb[c0w + nt * 16 + cl];

        #pragma unroll
        for (int mt = 0; mt < 2; ++mt)
            #pragma unroll
            for (int nt = 0; nt < 4; ++nt)
                #pragma unroll
                for (int r = 0; r < 4; ++r)
                    out[((size_t)b * NW + W0 + mt * 16 + kg * 4 + r) * ND + c0w + nt * 16 + cl]
                        = acc[mt][nt][r] + bv[nt];
    } else {
        const int wv = wave - 4;
        pool4(sb, 32 + wv * 8,     A1t, wv * 8,     base, lane);
        pool4(sb, 32 + wv * 8 + 4, A1t, wv * 8 + 4, base, lane);
    }
    __syncthreads();

    // ---- Stage 3: all 8 waves GEMM(A1t) 32x256; wave = 32x32 (2Mx2N) ----
    {
        const int c0w = wave * 32;
        const unsigned short* bgp = wt2 + (size_t)(wave * 2) * 12288 + kg * 128 + cl * 8;
        short8 a0f[2], a1f[2], b0f[2], b1f[2];
        f32x4 acc[2][2];
        #pragma unroll
        for (int mt = 0; mt < 2; ++mt)
            #pragma unroll
            for (int nt = 0; nt < 2; ++nt)
                #pragma unroll
                for (int r = 0; r < 4; ++r) acc[mt][nt][r] = 0.f;

#define LDA1(d, ks) { d[0] = *(const short8*)&A1t[cl][(ks) * 32 + kg * 8];    \
                      d[1] = *(const short8*)&A1t[16 + cl][(ks) * 32 + kg * 8]; }
#define LDB1(d, ks) { _Pragma("unroll")                                       \
                      for (int nt = 0; nt < 2; ++nt)                          \
                          d[nt] = *(const short8*)(bgp + nt * 12288 + (ks) * 512); }
#define MM1(a, bb) { _Pragma("unroll")                                        \
                     for (int mt = 0; mt < 2; ++mt)                           \
                         _Pragma("unroll")                                    \
                         for (int nt = 0; nt < 2; ++nt)                       \
                             acc[mt][nt] = __builtin_amdgcn_mfma_f32_16x16x32_bf16(a[mt], bb[nt], acc[mt][nt], 0, 0, 0); }

        LDA1(a0f, 0); LDB1(b0f, 0);
        #pragma unroll 1
        for (int i = 0; i < 12; ++i) {
            const int ks = 2 * i;
            LDA1(a1f, ks + 1); LDB1(b1f, ks + 1);
            MM1(a0f, b0f);
            if (i < 11) { LDA1(a0f, ks + 2); LDB1(b0f, ks + 2); }
            MM1(a1f, b1f);
        }
#undef LDA1
#undef LDB1
#undef MM1

        float bv[2];
        bv[0] = pb[c0w + cl];
        bv[1] = pb[c0w + 16 + cl];

        // C/D layout: col=lane&15, row=(lane>>4)*4+r  [proven R1-R30]
        #pragma unroll
        for (int mt = 0; mt < 2; ++mt)
            #pragma unroll
            for (int nt = 0; nt < 2; ++nt)
                #pragma unroll
                for (int r = 0; r < 4; ++r)
                    out[((size_t)b * NW + W0 + 32 + mt * 16 + kg * 4 + r) * ND + c0w + nt * 16 + cl]
                        = acc[mt][nt][r] + bv[nt];
    }
}

extern "C" void kernel_launch(void* const* d_in, const int* in_sizes, int n_in,
                              void* d_out, int out_size, void* d_ws, size_t ws_size,
                              hipStream_t stream) {
    const float* hs  = (const float*)d_in[0];
    const int*   wid = (const int*)d_in[1];
    const float* pw  = (const float*)d_in[2];
    const float* pb  = (const float*)d_in[3];
    float* out = (float*)d_out;

    unsigned short* wt2 = (unsigned short*)d_ws;     // 393216 B

    prep_wt2<<<192, 256, 0, stream>>>(pw, wt2);
    fused<<<NB * 4, 512, 0, stream>>>(hs, wid, wt2, pb, out);
}